// Round 12
// baseline (30.057 us; speedup 1.0000x reference)
//
#include <hip/hip_runtime.h>

// Problem constants (B=131072 rows, C=64 cols)
#define NROWS 131072
#define NCOLS 64
// kernS: streaming focal + mask production
#define SBLK 4096
#define STHR 256             // 4 waves; 1M threads, 8 elems each
// kernGBC: Gram from bitmasks + fused last-block finalize
#define GBLK 128
#define GTHR 1024            // 2048 waves total: 2 rows x 64 words each
// fallback (round-6 verified structure)
#define FNBLK 512
#define FNTHR 512
#define FNWAVES 8

typedef __attribute__((ext_vector_type(2))) float f32x2;

// Workspace layout (main path):
//   [0]      float pkF[4096]         (16 KB)
//   [16384]  u32   gS[64][64]        (16 KB, zeroed by kernS block 0)
//   [32768]  u32   gP[64][64]        (16 KB, zeroed by kernS block 0)
//   [49152]  u32   cnt               (zeroed by kernS block 0)
//   [65536]  u32   Mmv[4096][64][2]  (2 MB: per word, per col, {m,v})
// Coherence design (round-9 lesson): NO __threadfence (its buffer_wbl2/inv
// per block serialized kernG to 42 us). All cross-block communication is
// device-scope atomics (home = memory-side cache, coherent across XCDs):
// each block drains its atomicAdds (vmcnt(0) + barrier) BEFORE bumping cnt,
// so cnt==GBLK implies all adds visible; last block reads via agent-scope
// atomic loads (L1 bypass). Zero L2-writeback instructions anywhere.

// -------- Kernel S: minimal-issue focal stream + 32-bit mask words --------
// 8 elems/thread (4 loads upfront, ~50 VGPR -> launch_bounds(256,8)).
// Block b covers rows {16b..16b+15} u {65536+16b..+15}; one mask word
// (bit = k*16 + wv*4 + h) — row grouping is Gram-permutation-invariant.
// Focal per element (z2 = x*(2t-1)*log2e, d2=1+2^z2):
//   w = rcp(d2); core = log2(d2) - z2; wt = fma(t, pw-1, 1)
//   fsum += w^2*core*wt; fold ln2 once. f32x2 -> v_pk_* for non-trans ops.
__global__ __launch_bounds__(STHR, 8)
void kernS(const float* __restrict__ in, const float* __restrict__ tg,
           const float* __restrict__ pw, unsigned* __restrict__ Mmv,
           float* __restrict__ pkF, uint4* __restrict__ gZero) {
    __shared__ uint2 ldsM[4][64];        // [wave][col] = {m32, v32} partial
    __shared__ float fp[4];
    const int tid = threadIdx.x;
    if (blockIdx.x == 0) {               // zero gS,gP,cnt (36 KB region)
        const uint4 z4 = {0u, 0u, 0u, 0u};
#pragma unroll
        for (int k = 0; k < 9; ++k) gZero[tid + k * STHR] = z4;
    }
    const int gtid = blockIdx.x * STHR + tid;
    const int lane = tid & 63;
    const int wv = tid >> 6;             // 0..3
    const int h = lane >> 4;             // row phase 0..3
    const int c4 = (lane & 15) * 4;
    const int jc = c4 + h;               // owned column (permutation of 0..63)

    const float4 pwv = *reinterpret_cast<const float4*>(pw + c4);
    const f32x2 pmA = {pwv.x - 1.f, pwv.y - 1.f};
    const f32x2 pmB = {pwv.z - 1.f, pwv.w - 1.f};
    const float4* in4 = reinterpret_cast<const float4*>(in);
    const float4* tg4 = reinterpret_cast<const float4*>(tg);

    // all 4 loads upfront
    float4 xr[2], tr[2];
    xr[0] = in4[gtid];  xr[1] = in4[gtid + SBLK * STHR];
    tr[0] = tg4[gtid];  tr[1] = tg4[gtid + SBLK * STHR];

    f32x2 facc = {0.f, 0.f};
    unsigned m4[4] = {0u, 0u, 0u, 0u};
    unsigned v4[4] = {0u, 0u, 0u, 0u};
    const unsigned hb = (1u << h) << (wv * 4);   // this thread's k=0 bit

    auto pair = [&](float x0, float x1, float t0, float t1, f32x2 pm1,
                    unsigned bq, unsigned& mk0, unsigned& vk0,
                    unsigned& mk1, unsigned& vk1) {
        const f32x2 xv = {x0, x1};
        const f32x2 tv = {t0, t1};
        const f32x2 s2l = tv * 2.8853900817779268f - 1.4426950408889634f; // pk fma
        const f32x2 z2 = xv * s2l;                                        // pk mul
        f32x2 e2, w, lg;
        e2.x = exp2f(z2.x);  e2.y = exp2f(z2.y);                          // trans
        const f32x2 d2 = e2 + 1.f;                                        // pk add
        w.x = __builtin_amdgcn_rcpf(d2.x);  w.y = __builtin_amdgcn_rcpf(d2.y);
        lg.x = __log2f(d2.x);  lg.y = __log2f(d2.y);                      // trans
        const f32x2 core = lg - z2;                                       // pk
        const f32x2 wt = tv * pm1 + 1.f;                                  // pk fma
        const f32x2 w2c = (w * w) * core;                                 // 2x pk
        facc = w2c * wt + facc;                                           // pk fma
        const bool tb0 = t0 > 0.5f, tb1 = t1 > 0.5f;
        const bool p0 = z2.x >= 0.f, p1 = z2.y >= 0.f;
        mk0 |= tb0 ? bq : 0u;  vk0 |= (tb0 && p0) ? bq : 0u;
        mk1 |= tb1 ? bq : 0u;  vk1 |= (tb1 && p1) ? bq : 0u;
    };

#pragma unroll
    for (int k = 0; k < 2; ++k) {        // k=0: rows 16b+..; k=1: +65536
        const unsigned bq = hb << (k * 16);
        pair(xr[k].x, xr[k].y, tr[k].x, tr[k].y, pmA, bq, m4[0], v4[0], m4[1], v4[1]);
        pair(xr[k].z, xr[k].w, tr[k].z, tr[k].w, pmB, bq, m4[2], v4[2], m4[3], v4[3]);
    }
    float fsum = (facc.x + facc.y) * 0.6931471805599453f;  // fold ln2

    // OR-combine the 4 row-phases across lane groups (lanes l^16, l^32)
#pragma unroll
    for (int k = 0; k < 4; ++k) {
        m4[k] |= __shfl_xor(m4[k], 16, 64);
        m4[k] |= __shfl_xor(m4[k], 32, 64);
        v4[k] |= __shfl_xor(v4[k], 16, 64);
        v4[k] |= __shfl_xor(v4[k], 32, 64);
    }
    const unsigned m = (h & 2) ? ((h & 1) ? m4[3] : m4[2]) : ((h & 1) ? m4[1] : m4[0]);
    const unsigned v = (h & 2) ? ((h & 1) ? v4[3] : v4[2]) : ((h & 1) ? v4[1] : v4[0]);

    ldsM[wv][jc].x = m;                  // this wave's 8 bits of the word
    ldsM[wv][jc].y = v;

    // focal wave reduce
#pragma unroll
    for (int off = 32; off; off >>= 1) fsum += __shfl_down(fsum, off, 64);
    if (lane == 0) fp[wv] = fsum;
    __syncthreads();

    if (tid == 0) pkF[blockIdx.x] = fp[0] + fp[1] + fp[2] + fp[3];

    // OR 4 waves' partials -> one 32-bit word per col; coalesced 512 B store
    if (tid < 128) {
        const int col = tid >> 1;
        const int sel = tid & 1;
        const uint2 a0 = ldsM[0][col], a1 = ldsM[1][col];
        const uint2 a2 = ldsM[2][col], a3 = ldsM[3][col];
        const unsigned mm = a0.x | a1.x | a2.x | a3.x;
        const unsigned vv = a0.y | a1.y | a2.y | a3.y;
        Mmv[(size_t)blockIdx.x * 128 + tid] = sel ? vv : mm;
    }
}

// -------- Kernel GBC: Gram from bitmasks + fused last-block finalize --------
// 2048 waves: wave gw -> rows i0=2*(gw>>6), i0+1; words (gw&63)*64 .. +63.
// Lane = col j. S[i][j] += popc(m_i & m_j); P[i][j] += popc(v_i & (m_j & ~v_j)).
// Last block (atomic-only coherence, no fences) finalizes to out.
__global__ __launch_bounds__(GTHR, 2)
void kernGBC(const unsigned* __restrict__ Mmv,
             unsigned* __restrict__ gS, unsigned* __restrict__ gP,
             const float* __restrict__ pkF, unsigned* __restrict__ cnt,
             float* __restrict__ out) {
    const int tid = threadIdx.x;
    const int lane = tid & 63;
    const int gw = blockIdx.x * (GTHR / 64) + (tid >> 6);  // 0..2047
    const int i0 = (gw >> 6) * 2;        // 0,2,..,62 (wave-uniform)
    const int w0 = (gw & 63) * 64;
    const uint2* p = reinterpret_cast<const uint2*>(Mmv) + (size_t)w0 * 64 + lane;

    unsigned S0 = 0u, S1 = 0u, P0 = 0u, P1 = 0u;
#pragma unroll 8
    for (int t = 0; t < 64; ++t) {
        const uint2 mv = p[(size_t)t * 64];              // coalesced 512 B
        const unsigned wm = mv.x & ~mv.y;
        const unsigned mi0 = (unsigned)__builtin_amdgcn_readlane((int)mv.x, i0);
        const unsigned vi0 = (unsigned)__builtin_amdgcn_readlane((int)mv.y, i0);
        const unsigned mi1 = (unsigned)__builtin_amdgcn_readlane((int)mv.x, i0 + 1);
        const unsigned vi1 = (unsigned)__builtin_amdgcn_readlane((int)mv.y, i0 + 1);
        S0 += (unsigned)__popc(mi0 & mv.x);
        P0 += (unsigned)__popc(vi0 & wm);
        S1 += (unsigned)__popc(mi1 & mv.x);
        P1 += (unsigned)__popc(vi1 & wm);
    }
    atomicAdd(&gS[i0 * 64 + lane], S0);
    atomicAdd(&gS[(i0 + 1) * 64 + lane], S1);
    atomicAdd(&gP[i0 * 64 + lane], P0);
    atomicAdd(&gP[(i0 + 1) * 64 + lane], P1);

    // drain this wave's atomics; barrier drains all waves (compiler emits
    // waitcnt before s_barrier). NO threadfence -> no L2 writeback ops.
    asm volatile("s_waitcnt vmcnt(0)" ::: "memory");
    __syncthreads();
    __shared__ int isLast;
    if (tid == 0) isLast = (atomicAdd(cnt, 1u) == GBLK - 1) ? 1 : 0;
    __syncthreads();
    if (!isLast) return;

    // last block: all adds are complete at the coherent home point.
    // Read with agent-scope atomic loads (L1 bypass).
    double acc = 0.0;
#pragma unroll
    for (int kk = 0; kk < 4; ++kk) {     // 4096 cells / 1024 threads
        const int c = tid + kk * GTHR;
        const unsigned S = __hip_atomic_load(&gS[c], __ATOMIC_RELAXED,
                                             __HIP_MEMORY_SCOPE_AGENT);
        const unsigned P = __hip_atomic_load(&gP[c], __ATOMIC_RELAXED,
                                             __HIP_MEMORY_SCOPE_AGENT);
        const int i = c >> 6, j = c & 63;
        const float corr = (float)S * (1.0f / (float)NROWS);
        // penalty_total = 2 * sum A_ij P_ij, A = 0.5*corr thresholded => corr*P
        if (i != j && corr > 0.3f) acc += (double)corr * (double)P;
    }
#pragma unroll
    for (int kk = 0; kk < 4; ++kk)       // 4096 focal partials / 1024 threads
        acc += (double)pkF[tid + kk * GTHR];
#pragma unroll
    for (int off = 32; off; off >>= 1) acc += __shfl_down(acc, off, 64);
    __shared__ double wred[16];
    const int wv = tid >> 6;
    if (lane == 0) wred[wv] = acc;
    __syncthreads();
    if (tid < 16) {
        double tot = wred[tid];
#pragma unroll
        for (int off = 8; off; off >>= 1) tot += __shfl_down(tot, off, 64);
        if (tid == 0)
            out[0] = (float)(tot * (1.0 / (double)((size_t)NROWS * NCOLS)));
    }
}

// ================= fallback path (round-6 verified structure) =================
__global__ __launch_bounds__(FNTHR, 2)
void kernAfb(const float* __restrict__ in, const float* __restrict__ tg,
             const float* __restrict__ pw, float* __restrict__ pkF,
             unsigned* __restrict__ gS, unsigned* __restrict__ gP) {
    __shared__ unsigned maskbuf[FNWAVES][64][2];
    __shared__ float fpart[FNWAVES];
    const int tid = threadIdx.x;
    const int lane = tid & 63;
    const int wv = tid >> 6;
    const int h = lane >> 4;
    const int c4 = (lane & 15) * 4;
    const int jc = c4 + h;
    const int row0 = blockIdx.x * (FNWAVES * 32) + wv * 32;

    const float4 pw4 = *reinterpret_cast<const float4*>(pw + c4);
    const float4* inp = reinterpret_cast<const float4*>(in)
                        + (size_t)(row0 + h) * 16 + (lane & 15);
    const float4* tgp = reinterpret_cast<const float4*>(tg)
                        + (size_t)(row0 + h) * 16 + (lane & 15);
    float4 xr[8], tr[8];
#pragma unroll
    for (int q = 0; q < 8; ++q) xr[q] = inp[(size_t)q * 64];
#pragma unroll
    for (int q = 0; q < 8; ++q) tr[q] = tgp[(size_t)q * 64];

    float fsum = 0.f;
    unsigned m4[4] = {0u, 0u, 0u, 0u};
    unsigned v4[4] = {0u, 0u, 0u, 0u};
    const unsigned hbit = 1u << h;
    auto elem = [&](float x, float t, float pwc, unsigned bq, unsigned& mk, unsigned& vk) {
        float ax = fabsf(x);
        float e = __expf(-ax);
        float L = __logf(1.f + e);
        float inv = __builtin_amdgcn_rcpf(1.f + e);
        float qq = e * inv;
        bool tb = t > 0.5f;
        bool pb = x >= 0.f;
        float w = (tb == pb) ? qq : inv;
        float bce = tb ? pwc * (L + fmaxf(-x, 0.f)) : (L + fmaxf(x, 0.f));
        fsum += w * w * bce;
        mk |= tb ? bq : 0u;
        vk |= (tb && pb) ? bq : 0u;
    };
#pragma unroll
    for (int q = 0; q < 8; ++q) {
        const unsigned bq = hbit << (4 * q);
        elem(xr[q].x, tr[q].x, pw4.x, bq, m4[0], v4[0]);
        elem(xr[q].y, tr[q].y, pw4.y, bq, m4[1], v4[1]);
        elem(xr[q].z, tr[q].z, pw4.z, bq, m4[2], v4[2]);
        elem(xr[q].w, tr[q].w, pw4.w, bq, m4[3], v4[3]);
    }
#pragma unroll
    for (int k = 0; k < 4; ++k) {
        m4[k] |= __shfl_xor(m4[k], 16, 64);
        m4[k] |= __shfl_xor(m4[k], 32, 64);
        v4[k] |= __shfl_xor(v4[k], 16, 64);
        v4[k] |= __shfl_xor(v4[k], 32, 64);
    }
    const unsigned m = (h & 2) ? ((h & 1) ? m4[3] : m4[2]) : ((h & 1) ? m4[1] : m4[0]);
    const unsigned v = (h & 2) ? ((h & 1) ? v4[3] : v4[2]) : ((h & 1) ? v4[1] : v4[0]);
    maskbuf[wv][jc][0] = m;
    maskbuf[wv][jc][1] = v;
#pragma unroll
    for (int off = 32; off; off >>= 1) fsum += __shfl_down(fsum, off, 64);
    if (lane == 0) fpart[wv] = fsum;
    __syncthreads();
    if (tid == 0) {
        float tot = 0.f;
#pragma unroll
        for (int k = 0; k < FNWAVES; ++k) tot += fpart[k];
        pkF[blockIdx.x] = tot;
    }
    unsigned aS[8] = {0u,0u,0u,0u,0u,0u,0u,0u};
    unsigned aP[8] = {0u,0u,0u,0u,0u,0u,0u,0u};
    const int a0 = wv * 8;
#pragma unroll
    for (int ww = 0; ww < FNWAVES; ++ww) {
        const unsigned mw = maskbuf[ww][lane][0];
        const unsigned vw = maskbuf[ww][lane][1];
        const unsigned wmw = mw & ~vw;
#pragma unroll
        for (int r = 0; r < 8; ++r) {
            const unsigned mi = maskbuf[ww][a0 + r][0];
            const unsigned vi = maskbuf[ww][a0 + r][1];
            aS[r] += (unsigned)__popc(mi & mw);
            aP[r] += (unsigned)__popc(vi & wmw);
        }
    }
#pragma unroll
    for (int r = 0; r < 8; ++r) {
        atomicAdd(&gS[(a0 + r) * 64 + lane], aS[r]);
        atomicAdd(&gP[(a0 + r) * 64 + lane], aP[r]);
    }
}

__global__ __launch_bounds__(1024)
void kernWfb(const unsigned* __restrict__ gS, const unsigned* __restrict__ gP,
             const float* __restrict__ pkF, float* __restrict__ out) {
    const int tid = threadIdx.x;
    double acc = 0.0;
#pragma unroll
    for (int kk = 0; kk < 4; ++kk) {
        const int c = tid + kk * 1024;
        const unsigned S = gS[c], P = gP[c];
        const int i = c >> 6, j = c & 63;
        const float corr = (float)S * (1.0f / (float)NROWS);
        if (i != j && corr > 0.3f) acc += (double)corr * (double)P;
    }
    if (tid < FNBLK) acc += (double)pkF[tid];
#pragma unroll
    for (int off = 32; off; off >>= 1) acc += __shfl_down(acc, off, 64);
    __shared__ double wred[16];
    const int lane = tid & 63, wv = tid >> 6;
    if (lane == 0) wred[wv] = acc;
    __syncthreads();
    if (tid < 16) {
        double tot = wred[tid];
#pragma unroll
        for (int off = 8; off; off >>= 1) tot += __shfl_down(tot, off, 64);
        if (tid == 0)
            out[0] = (float)(tot * (1.0 / (double)((size_t)NROWS * NCOLS)));
    }
}

extern "C" void kernel_launch(void* const* d_in, const int* in_sizes, int n_in,
                              void* d_out, int out_size, void* d_ws, size_t ws_size,
                              hipStream_t stream) {
    const float* in = (const float*)d_in[0];
    const float* tg = (const float*)d_in[1];
    const float* pw = (const float*)d_in[2];
    float* out = (float*)d_out;
    char* ws = (char*)d_ws;

    float* pkF = (float*)ws;                           // 16 KB
    unsigned* gS = (unsigned*)(ws + 16384);            // 16 KB
    unsigned* gP = (unsigned*)(ws + 32768);            // 16 KB
    unsigned* cnt = (unsigned*)(ws + 49152);           // 4 B (zeroed by kernS)
    unsigned* Mmv = (unsigned*)(ws + 65536);           // 2 MB
    const size_t need = 65536 + (size_t)4096 * 64 * 2 * sizeof(unsigned);

    if (ws_size >= need) {
        kernS<<<SBLK, STHR, 0, stream>>>(in, tg, pw, Mmv, pkF, (uint4*)gS);
        kernGBC<<<GBLK, GTHR, 0, stream>>>(Mmv, gS, gP, pkF, cnt, out);
    } else {
        hipMemsetAsync(ws + 16384, 0, 32768, stream);
        kernAfb<<<FNBLK, FNTHR, 0, stream>>>(in, tg, pw, pkF, gS, gP);
        kernWfb<<<1, 1024, 0, stream>>>(gS, gP, pkF, out);
    }
}

// Round 14
// 27.113 us; speedup vs baseline: 1.1086x; 1.1086x over previous
//
#include <hip/hip_runtime.h>

// Problem constants (B=131072 rows, C=64 cols)
#define NROWS 131072
#define NCOLS 64
// kernS: streaming focal + mask production
#define SBLK 4096
#define STHR 256             // 4 waves; 1M threads, 8 elems each
// kernG: Gram from bitmasks
#define GBLK 512
#define GTHR 256             // 2048 waves: 2 rows x 64 words each
// fallback (round-6 verified structure)
#define FNBLK 512
#define FNTHR 512
#define FNWAVES 8

typedef __attribute__((ext_vector_type(2))) float f32x2;
typedef __attribute__((ext_vector_type(4))) float f32x4;   // native clang vector
                                                           // (nontemporal builtin
                                                           // rejects HIP float4)

// Workspace layout (main path):
//   [0]      float pkF[4096]         (16 KB)
//   [16384]  u32   gS[64][64]        (16 KB, zeroed by kernS block 0)
//   [32768]  u32   gP[64][64]        (16 KB, zeroed by kernS block 0)
//   [65536]  u32   Mmv[4096][64][2]  (2 MB: per word, per col, {m,v})
// Ledger notes: round-9: per-block __threadfence (buffer_wbl2/inv) = +39 us,
// never fuse via device fences. round-12: atomic-only last-block fusion is
// correct but net +2 us vs separate dispatches. 3-dispatch is the optimum.

// -------- Kernel S: minimal-issue focal stream + 32-bit mask words --------
// 8 elems/thread (4 NON-TEMPORAL loads upfront; data is read exactly once ->
// nt bypasses cache fill). ~50 VGPR -> launch_bounds(256,8), 8 waves/SIMD.
// Block b covers rows {16b..16b+15} u {65536+16b..+15}; one mask word
// (bit = k*16 + wv*4 + h) — row grouping is Gram-permutation-invariant.
// Focal per element (z2 = x*(2t-1)*log2e, d2=1+2^z2):
//   w = rcp(d2); core = log2(d2) - z2; wt = fma(t, pw-1, 1)
//   fsum += w^2*core*wt; fold ln2 once. f32x2 -> v_pk_* for non-trans ops.
__global__ __launch_bounds__(STHR, 8)
void kernS(const float* __restrict__ in, const float* __restrict__ tg,
           const float* __restrict__ pw, unsigned* __restrict__ Mmv,
           float* __restrict__ pkF, uint4* __restrict__ gZero) {
    __shared__ uint2 ldsM[4][64];        // [wave][col] = {m32, v32} partial
    __shared__ float fp[4];
    const int tid = threadIdx.x;
    if (blockIdx.x == 0) {               // zero gS,gP (32 KB) - kills the memset
        const uint4 z4 = {0u, 0u, 0u, 0u};
#pragma unroll
        for (int k = 0; k < 8; ++k) gZero[tid + k * STHR] = z4;
    }
    const int gtid = blockIdx.x * STHR + tid;
    const int lane = tid & 63;
    const int wv = tid >> 6;             // 0..3
    const int h = lane >> 4;             // row phase 0..3
    const int c4 = (lane & 15) * 4;
    const int jc = c4 + h;               // owned column (permutation of 0..63)

    const float4 pwv = *reinterpret_cast<const float4*>(pw + c4);
    const f32x2 pmA = {pwv.x - 1.f, pwv.y - 1.f};
    const f32x2 pmB = {pwv.z - 1.f, pwv.w - 1.f};
    const f32x4* in4 = reinterpret_cast<const f32x4*>(in);
    const f32x4* tg4 = reinterpret_cast<const f32x4*>(tg);

    // all 4 loads upfront, non-temporal (single-pass stream)
    f32x4 xr[2], tr[2];
    xr[0] = __builtin_nontemporal_load(&in4[gtid]);
    xr[1] = __builtin_nontemporal_load(&in4[gtid + SBLK * STHR]);
    tr[0] = __builtin_nontemporal_load(&tg4[gtid]);
    tr[1] = __builtin_nontemporal_load(&tg4[gtid + SBLK * STHR]);

    f32x2 facc = {0.f, 0.f};
    unsigned m4[4] = {0u, 0u, 0u, 0u};
    unsigned v4[4] = {0u, 0u, 0u, 0u};
    const unsigned hb = (1u << h) << (wv * 4);   // this thread's k=0 bit

    auto pair = [&](float x0, float x1, float t0, float t1, f32x2 pm1,
                    unsigned bq, unsigned& mk0, unsigned& vk0,
                    unsigned& mk1, unsigned& vk1) {
        const f32x2 xv = {x0, x1};
        const f32x2 tv = {t0, t1};
        const f32x2 s2l = tv * 2.8853900817779268f - 1.4426950408889634f; // pk fma
        const f32x2 z2 = xv * s2l;                                        // pk mul
        f32x2 e2, w, lg;
        e2.x = exp2f(z2.x);  e2.y = exp2f(z2.y);                          // trans
        const f32x2 d2 = e2 + 1.f;                                        // pk add
        w.x = __builtin_amdgcn_rcpf(d2.x);  w.y = __builtin_amdgcn_rcpf(d2.y);
        lg.x = __log2f(d2.x);  lg.y = __log2f(d2.y);                      // trans
        const f32x2 core = lg - z2;                                       // pk
        const f32x2 wt = tv * pm1 + 1.f;                                  // pk fma
        const f32x2 w2c = (w * w) * core;                                 // 2x pk
        facc = w2c * wt + facc;                                           // pk fma
        const bool tb0 = t0 > 0.5f, tb1 = t1 > 0.5f;
        const bool p0 = z2.x >= 0.f, p1 = z2.y >= 0.f;
        mk0 |= tb0 ? bq : 0u;  vk0 |= (tb0 && p0) ? bq : 0u;
        mk1 |= tb1 ? bq : 0u;  vk1 |= (tb1 && p1) ? bq : 0u;
    };

#pragma unroll
    for (int k = 0; k < 2; ++k) {        // k=0: rows 16b+..; k=1: +65536
        const unsigned bq = hb << (k * 16);
        pair(xr[k].x, xr[k].y, tr[k].x, tr[k].y, pmA, bq, m4[0], v4[0], m4[1], v4[1]);
        pair(xr[k].z, xr[k].w, tr[k].z, tr[k].w, pmB, bq, m4[2], v4[2], m4[3], v4[3]);
    }
    float fsum = (facc.x + facc.y) * 0.6931471805599453f;  // fold ln2

    // OR-combine the 4 row-phases across lane groups (lanes l^16, l^32)
#pragma unroll
    for (int k = 0; k < 4; ++k) {
        m4[k] |= __shfl_xor(m4[k], 16, 64);
        m4[k] |= __shfl_xor(m4[k], 32, 64);
        v4[k] |= __shfl_xor(v4[k], 16, 64);
        v4[k] |= __shfl_xor(v4[k], 32, 64);
    }
    const unsigned m = (h & 2) ? ((h & 1) ? m4[3] : m4[2]) : ((h & 1) ? m4[1] : m4[0]);
    const unsigned v = (h & 2) ? ((h & 1) ? v4[3] : v4[2]) : ((h & 1) ? v4[1] : v4[0]);

    ldsM[wv][jc].x = m;                  // this wave's 8 bits of the word
    ldsM[wv][jc].y = v;

    // focal wave reduce
#pragma unroll
    for (int off = 32; off; off >>= 1) fsum += __shfl_down(fsum, off, 64);
    if (lane == 0) fp[wv] = fsum;
    __syncthreads();

    if (tid == 0) pkF[blockIdx.x] = fp[0] + fp[1] + fp[2] + fp[3];

    // OR 4 waves' partials -> one 32-bit word per col; coalesced 512 B store
    if (tid < 128) {
        const int col = tid >> 1;
        const int sel = tid & 1;
        const uint2 a0 = ldsM[0][col], a1 = ldsM[1][col];
        const uint2 a2 = ldsM[2][col], a3 = ldsM[3][col];
        const unsigned mm = a0.x | a1.x | a2.x | a3.x;
        const unsigned vv = a0.y | a1.y | a2.y | a3.y;
        Mmv[(size_t)blockIdx.x * 128 + tid] = sel ? vv : mm;
    }
}

// -------- Kernel G: Gram from bitmasks (pure, no fences) --------
// 2048 waves: wave gw -> rows i0=2*(gw>>6), i0+1; words (gw&63)*64 .. +63.
// Lane = col j. S[i][j] += popc(m_i & m_j); P[i][j] += popc(v_i & (m_j & ~v_j)).
__global__ __launch_bounds__(GTHR, 8)
void kernG(const unsigned* __restrict__ Mmv,
           unsigned* __restrict__ gS, unsigned* __restrict__ gP) {
    const int tid = threadIdx.x;
    const int lane = tid & 63;
    const int gw = blockIdx.x * (GTHR / 64) + (tid >> 6);  // 0..2047
    const int i0 = (gw >> 6) * 2;        // 0,2,..,62 (wave-uniform)
    const int w0 = (gw & 63) * 64;
    const uint2* p = reinterpret_cast<const uint2*>(Mmv) + (size_t)w0 * 64 + lane;

    unsigned S0 = 0u, S1 = 0u, P0 = 0u, P1 = 0u;
#pragma unroll 8
    for (int t = 0; t < 64; ++t) {
        const uint2 mv = p[(size_t)t * 64];              // coalesced 512 B
        const unsigned wm = mv.x & ~mv.y;
        const unsigned mi0 = (unsigned)__builtin_amdgcn_readlane((int)mv.x, i0);
        const unsigned vi0 = (unsigned)__builtin_amdgcn_readlane((int)mv.y, i0);
        const unsigned mi1 = (unsigned)__builtin_amdgcn_readlane((int)mv.x, i0 + 1);
        const unsigned vi1 = (unsigned)__builtin_amdgcn_readlane((int)mv.y, i0 + 1);
        S0 += (unsigned)__popc(mi0 & mv.x);
        P0 += (unsigned)__popc(vi0 & wm);
        S1 += (unsigned)__popc(mi1 & mv.x);
        P1 += (unsigned)__popc(vi1 & wm);
    }
    atomicAdd(&gS[i0 * 64 + lane], S0);
    atomicAdd(&gS[(i0 + 1) * 64 + lane], S1);
    atomicAdd(&gP[i0 * 64 + lane], P0);
    atomicAdd(&gP[(i0 + 1) * 64 + lane], P1);
}

// -------- BC: penalty + focal + output (1 block) --------
__global__ __launch_bounds__(1024)
void kernBC(const unsigned* __restrict__ gS, const unsigned* __restrict__ gP,
            const float* __restrict__ pkF, float* __restrict__ out) {
    const int tid = threadIdx.x;
    double acc = 0.0;
#pragma unroll
    for (int kk = 0; kk < 4; ++kk) {
        const int c = tid + kk * 1024;
        const unsigned S = gS[c], P = gP[c];
        const int i = c >> 6, j = c & 63;
        const float corr = (float)S * (1.0f / (float)NROWS);
        // penalty_total = 2 * sum A_ij P_ij, A = 0.5*corr thresholded => corr*P
        if (i != j && corr > 0.3f) acc += (double)corr * (double)P;
    }
#pragma unroll
    for (int kk = 0; kk < 4; ++kk)
        acc += (double)pkF[tid + kk * 1024];
#pragma unroll
    for (int off = 32; off; off >>= 1) acc += __shfl_down(acc, off, 64);
    __shared__ double wred[16];
    const int lane = tid & 63, wv = tid >> 6;
    if (lane == 0) wred[wv] = acc;
    __syncthreads();
    if (tid < 16) {
        double tot = wred[tid];
#pragma unroll
        for (int off = 8; off; off >>= 1) tot += __shfl_down(tot, off, 64);
        if (tid == 0)
            out[0] = (float)(tot * (1.0 / (double)((size_t)NROWS * NCOLS)));
    }
}

// ================= fallback path (round-6 verified structure) =================
__global__ __launch_bounds__(FNTHR, 2)
void kernAfb(const float* __restrict__ in, const float* __restrict__ tg,
             const float* __restrict__ pw, float* __restrict__ pkF,
             unsigned* __restrict__ gS, unsigned* __restrict__ gP) {
    __shared__ unsigned maskbuf[FNWAVES][64][2];
    __shared__ float fpart[FNWAVES];
    const int tid = threadIdx.x;
    const int lane = tid & 63;
    const int wv = tid >> 6;
    const int h = lane >> 4;
    const int c4 = (lane & 15) * 4;
    const int jc = c4 + h;
    const int row0 = blockIdx.x * (FNWAVES * 32) + wv * 32;

    const float4 pw4 = *reinterpret_cast<const float4*>(pw + c4);
    const float4* inp = reinterpret_cast<const float4*>(in)
                        + (size_t)(row0 + h) * 16 + (lane & 15);
    const float4* tgp = reinterpret_cast<const float4*>(tg)
                        + (size_t)(row0 + h) * 16 + (lane & 15);
    float4 xr[8], tr[8];
#pragma unroll
    for (int q = 0; q < 8; ++q) xr[q] = inp[(size_t)q * 64];
#pragma unroll
    for (int q = 0; q < 8; ++q) tr[q] = tgp[(size_t)q * 64];

    float fsum = 0.f;
    unsigned m4[4] = {0u, 0u, 0u, 0u};
    unsigned v4[4] = {0u, 0u, 0u, 0u};
    const unsigned hbit = 1u << h;
    auto elem = [&](float x, float t, float pwc, unsigned bq, unsigned& mk, unsigned& vk) {
        float ax = fabsf(x);
        float e = __expf(-ax);
        float L = __logf(1.f + e);
        float inv = __builtin_amdgcn_rcpf(1.f + e);
        float qq = e * inv;
        bool tb = t > 0.5f;
        bool pb = x >= 0.f;
        float w = (tb == pb) ? qq : inv;
        float bce = tb ? pwc * (L + fmaxf(-x, 0.f)) : (L + fmaxf(x, 0.f));
        fsum += w * w * bce;
        mk |= tb ? bq : 0u;
        vk |= (tb && pb) ? bq : 0u;
    };
#pragma unroll
    for (int q = 0; q < 8; ++q) {
        const unsigned bq = hbit << (4 * q);
        elem(xr[q].x, tr[q].x, pw4.x, bq, m4[0], v4[0]);
        elem(xr[q].y, tr[q].y, pw4.y, bq, m4[1], v4[1]);
        elem(xr[q].z, tr[q].z, pw4.z, bq, m4[2], v4[2]);
        elem(xr[q].w, tr[q].w, pw4.w, bq, m4[3], v4[3]);
    }
#pragma unroll
    for (int k = 0; k < 4; ++k) {
        m4[k] |= __shfl_xor(m4[k], 16, 64);
        m4[k] |= __shfl_xor(m4[k], 32, 64);
        v4[k] |= __shfl_xor(v4[k], 16, 64);
        v4[k] |= __shfl_xor(v4[k], 32, 64);
    }
    const unsigned m = (h & 2) ? ((h & 1) ? m4[3] : m4[2]) : ((h & 1) ? m4[1] : m4[0]);
    const unsigned v = (h & 2) ? ((h & 1) ? v4[3] : v4[2]) : ((h & 1) ? v4[1] : v4[0]);
    maskbuf[wv][jc][0] = m;
    maskbuf[wv][jc][1] = v;
#pragma unroll
    for (int off = 32; off; off >>= 1) fsum += __shfl_down(fsum, off, 64);
    if (lane == 0) fpart[wv] = fsum;
    __syncthreads();
    if (tid == 0) {
        float tot = 0.f;
#pragma unroll
        for (int k = 0; k < FNWAVES; ++k) tot += fpart[k];
        pkF[blockIdx.x] = tot;
    }
    unsigned aS[8] = {0u,0u,0u,0u,0u,0u,0u,0u};
    unsigned aP[8] = {0u,0u,0u,0u,0u,0u,0u,0u};
    const int a0 = wv * 8;
#pragma unroll
    for (int ww = 0; ww < FNWAVES; ++ww) {
        const unsigned mw = maskbuf[ww][lane][0];
        const unsigned vw = maskbuf[ww][lane][1];
        const unsigned wmw = mw & ~vw;
#pragma unroll
        for (int r = 0; r < 8; ++r) {
            const unsigned mi = maskbuf[ww][a0 + r][0];
            const unsigned vi = maskbuf[ww][a0 + r][1];
            aS[r] += (unsigned)__popc(mi & mw);
            aP[r] += (unsigned)__popc(vi & wmw);
        }
    }
#pragma unroll
    for (int r = 0; r < 8; ++r) {
        atomicAdd(&gS[(a0 + r) * 64 + lane], aS[r]);
        atomicAdd(&gP[(a0 + r) * 64 + lane], aP[r]);
    }
}

__global__ __launch_bounds__(1024)
void kernWfb(const unsigned* __restrict__ gS, const unsigned* __restrict__ gP,
             const float* __restrict__ pkF, float* __restrict__ out) {
    const int tid = threadIdx.x;
    double acc = 0.0;
#pragma unroll
    for (int kk = 0; kk < 4; ++kk) {
        const int c = tid + kk * 1024;
        const unsigned S = gS[c], P = gP[c];
        const int i = c >> 6, j = c & 63;
        const float corr = (float)S * (1.0f / (float)NROWS);
        if (i != j && corr > 0.3f) acc += (double)corr * (double)P;
    }
    if (tid < FNBLK) acc += (double)pkF[tid];
#pragma unroll
    for (int off = 32; off; off >>= 1) acc += __shfl_down(acc, off, 64);
    __shared__ double wred[16];
    const int lane = tid & 63, wv = tid >> 6;
    if (lane == 0) wred[wv] = acc;
    __syncthreads();
    if (tid < 16) {
        double tot = wred[tid];
#pragma unroll
        for (int off = 8; off; off >>= 1) tot += __shfl_down(tot, off, 64);
        if (tid == 0)
            out[0] = (float)(tot * (1.0 / (double)((size_t)NROWS * NCOLS)));
    }
}

extern "C" void kernel_launch(void* const* d_in, const int* in_sizes, int n_in,
                              void* d_out, int out_size, void* d_ws, size_t ws_size,
                              hipStream_t stream) {
    const float* in = (const float*)d_in[0];
    const float* tg = (const float*)d_in[1];
    const float* pw = (const float*)d_in[2];
    float* out = (float*)d_out;
    char* ws = (char*)d_ws;

    float* pkF = (float*)ws;                           // 16 KB
    unsigned* gS = (unsigned*)(ws + 16384);            // 16 KB
    unsigned* gP = (unsigned*)(ws + 32768);            // 16 KB
    unsigned* Mmv = (unsigned*)(ws + 65536);           // 2 MB
    const size_t need = 65536 + (size_t)4096 * 64 * 2 * sizeof(unsigned);

    if (ws_size >= need) {
        kernS<<<SBLK, STHR, 0, stream>>>(in, tg, pw, Mmv, pkF, (uint4*)gS);
        kernG<<<GBLK, GTHR, 0, stream>>>(Mmv, gS, gP);
        kernBC<<<1, 1024, 0, stream>>>(gS, gP, pkF, out);
    } else {
        hipMemsetAsync(ws + 16384, 0, 32768, stream);
        kernAfb<<<FNBLK, FNTHR, 0, stream>>>(in, tg, pw, pkF, gS, gP);
        kernWfb<<<1, 1024, 0, stream>>>(gS, gP, pkF, out);
    }
}